// Round 6
// baseline (148.229 us; speedup 1.0000x reference)
//
#include <hip/hip_runtime.h>

#define NH 12

typedef __bf16 bf16x8 __attribute__((ext_vector_type(8)));
typedef __bf16 bf16x4 __attribute__((ext_vector_type(4)));
typedef float f32x4 __attribute__((ext_vector_type(4)));

typedef const __attribute__((address_space(1))) void* gas_ptr;
typedef __attribute__((address_space(3))) void* las_ptr;

__device__ __forceinline__ void gload_lds16(const __bf16* g, __bf16* l) {
    __builtin_amdgcn_global_load_lds((gas_ptr)g, (las_ptr)l, 16, 0, 0);
}

// Q scale folded with log2(e): attention runs in exp2 domain.
#define QSCALE 0.18033688011112042f   // 0.125 * log2(e)

// ---------------- fp32 -> bf16 conversion (vectorized: 8 elems/thread/iter) ----------------
__global__ void convert_kernel(const float* __restrict__ hs,
                               const float* __restrict__ w1,
                               const float* __restrict__ w2,
                               __bf16* __restrict__ xh,
                               __bf16* __restrict__ wq,
                               __bf16* __restrict__ wo) {
    const long long C0 = 786432;   // 6291456/8
    const long long C1 = 221184;   // 1769472/8
    const long long C2 = 73728;    // 589824/8
    long long i = (long long)blockIdx.x * blockDim.x + threadIdx.x;
    const long long stride = (long long)gridDim.x * blockDim.x;
    for (; i < C0 + C1 + C2; i += stride) {
        const float* src; __bf16* dst; long long j;
        if (i < C0)           { src = hs; dst = xh; j = i; }
        else if (i < C0 + C1) { src = w1; dst = wq; j = i - C0; }
        else                  { src = w2; dst = wo; j = i - C0 - C1; }
        f32x4 v0 = *(const f32x4*)(src + j * 8);
        f32x4 v1 = *(const f32x4*)(src + j * 8 + 4);
        bf16x8 o;
#pragma unroll
        for (int r = 0; r < 4; r++) { o[r] = (__bf16)v0[r]; o[4 + r] = (__bf16)v1[r]; }
        *(bf16x8*)(dst + j * 8) = o;
    }
}

// ---------------- NT bf16 MFMA GEMM: C = A(MxK) * B(NxK)^T + bias ----------------
// 512 threads / 8 waves (2x4) per 128x128 tile, BK=64, XOR-swizzled LDS.
// NBUF=4: deep pipeline, prefetch 3 tiles ahead, counted vmcnt + raw s_barrier
//         (loads stay in flight across barriers; never vmcnt(0) in steady state).
// NBUF=2: classic double-buffer with __syncthreads (for small grids where
//         2 blocks/CU residency matters more than pipeline depth).
template <int MODE, int NBUF>
__global__ __launch_bounds__(512) void gemm_nt(
    const __bf16* __restrict__ A, const __bf16* __restrict__ Bm,
    const float* __restrict__ bias,
    __bf16* __restrict__ qb, __bf16* __restrict__ kb, __bf16* __restrict__ vT,
    float* __restrict__ outf, int M, int N, int K, int NXB)
{
    __shared__ __bf16 As[NBUF][128 * 64];
    __shared__ __bf16 Bs[NBUF][128 * 64];
    const int t = threadIdx.x;
    const int lane = t & 63;
    const int w = t >> 6;
    const int wr = w >> 2, wc = w & 3;     // 2 x 4 wave grid; wave tile 64 x 32
    const int fr = lane & 15, g4 = lane >> 4;

    const int cpx = gridDim.x >> 3;
    const int orig = blockIdx.x;
    const int swz = (orig & 7) * cpx + (orig >> 3);
    const int bx = swz % NXB, by = swz / NXB;
    const int m0 = by * 128, n0 = bx * 128;

    f32x4 acc[4][2];
    const f32x4 z4 = {0.f, 0.f, 0.f, 0.f};
#pragma unroll
    for (int i = 0; i < 4; i++)
#pragma unroll
        for (int j = 0; j < 2; j++) acc[i][j] = z4;

    const int kSteps = K >> 6;

    // stage K-tile tk into LDS buffer b (2 A-chunks + 2 B-chunks per thread)
    auto stage = [&](int tk, int b) {
#pragma unroll
        for (int i = 0; i < 2; i++) {
            const int c = i * 512 + t;
            const int row = c >> 3;
            const int cb = ((c & 7) ^ (row & 7)) * 8;   // pre-swizzled source chunk
            gload_lds16(A  + (size_t)(m0 + row) * K + tk * 64 + cb, &As[b][c * 8]);
            gload_lds16(Bm + (size_t)(n0 + row) * K + tk * 64 + cb, &Bs[b][c * 8]);
        }
    };

    // fragments + 16 MFMAs for buffer `cur`
    auto compute = [&](int cur) {
#pragma unroll
        for (int h = 0; h < 2; h++) {
            bf16x8 af[4], bfr[2];
#pragma unroll
            for (int i = 0; i < 4; i++) {
                const int r = wr * 64 + i * 16 + fr;
                af[i] = *(const bf16x8*)&As[cur][r * 64 + (((h * 4 + g4) ^ (r & 7)) * 8)];
            }
#pragma unroll
            for (int j = 0; j < 2; j++) {
                const int r = wc * 32 + j * 16 + fr;
                bfr[j] = *(const bf16x8*)&Bs[cur][r * 64 + (((h * 4 + g4) ^ (r & 7)) * 8)];
            }
            __builtin_amdgcn_s_setprio(1);
#pragma unroll
            for (int i = 0; i < 4; i++)
#pragma unroll
                for (int j = 0; j < 2; j++)
                    acc[i][j] = __builtin_amdgcn_mfma_f32_16x16x32_bf16(af[i], bfr[j], acc[i][j], 0, 0, 0);
            __builtin_amdgcn_s_setprio(0);
        }
    };

    if constexpr (NBUF == 4) {
        // prologue: stage tiles 0..2 (12 loads in flight), wait tile 0 only
        stage(0, 0);
        if (kSteps > 1) stage(1, 1);
        if (kSteps > 2) stage(2, 2);
        if (kSteps > 2) asm volatile("s_waitcnt vmcnt(8)" ::: "memory");
        else            asm volatile("s_waitcnt vmcnt(0)" ::: "memory");
        __builtin_amdgcn_s_barrier();
        __builtin_amdgcn_sched_barrier(0);

        for (int ks = 0; ks < kSteps; ks++) {
            const int cur = ks & 3;
            // safe: buf[(ks+3)&3] was last READ in iter ks-1; those ds_reads
            // completed before barrier B_{ks-1}, which all waves have passed.
            if (ks + 3 < kSteps) stage(ks + 3, (ks + 3) & 3);

            compute(cur);

            const int rem = kSteps - 1 - ks;   // tiles still outstanding
            if (rem >= 3)      asm volatile("s_waitcnt vmcnt(8)" ::: "memory");
            else if (rem == 2) asm volatile("s_waitcnt vmcnt(4)" ::: "memory");
            else if (rem == 1) asm volatile("s_waitcnt vmcnt(0)" ::: "memory");
            if (rem >= 1) {
                __builtin_amdgcn_s_barrier();
                __builtin_amdgcn_sched_barrier(0);
            }
        }
    } else {
        // classic double-buffer, 1 __syncthreads per K-step
        stage(0, 0);
        __syncthreads();
        int cur = 0;
        for (int ks = 0; ks < kSteps; ks++) {
            if (ks < kSteps - 1) stage(ks + 1, cur ^ 1);
            compute(cur);
            __syncthreads();
            cur ^= 1;
        }
    }

#pragma unroll
    for (int j = 0; j < 2; j++) {
        const int gc = n0 + wc * 32 + j * 16 + fr;
        const float bv = bias[gc];
        int which = 0, head = 0, dim = 0;
        if (MODE == 0) {
            which = gc / 768;
            const int jj = gc - which * 768;
            head = jj >> 6; dim = jj & 63;
        }
#pragma unroll
        for (int i = 0; i < 4; i++)
#pragma unroll
            for (int r = 0; r < 4; r++) {
                const int gr = m0 + wr * 64 + i * 16 + g4 * 4 + r;
                const float val = acc[i][j][r] + bv;
                if (MODE == 0) {
                    const int s = gr >> 3, b = gr & 7;
                    const size_t n = (size_t)(b * NH + head);
                    if (which == 0)      qb[(n * 1024 + s) * 64 + dim] = (__bf16)(val * QSCALE);
                    else if (which == 1) kb[(n * 1024 + s) * 64 + dim] = (__bf16)val;
                    else                 vT[(n * 64 + dim) * 1024 + s] = (__bf16)val;
                } else {
                    outf[(size_t)gr * N + gc] = val;
                }
            }
    }
}

// ---------------- flash attention ----------------
__global__ __launch_bounds__(512) void attn_kernel(
    const __bf16* __restrict__ qb, const __bf16* __restrict__ kb,
    const __bf16* __restrict__ vT, __bf16* __restrict__ ctx)
{
    __shared__ __bf16 Kl[2][64 * 64];
    __shared__ __bf16 Vl[2][64 * 64];
    __shared__ __bf16 Pl[8][16 * 64];
    const int t = threadIdx.x, lane = t & 63, w = t >> 6;

    const int orig = blockIdx.x;
    const int swz = (orig & 7) * 96 + (orig >> 3);
    const int n = swz >> 3;
    const int q0 = (swz & 7) * 128;
    const int fr = lane & 15, g4 = lane >> 4;
    const int fx = fr & 7;

    const __bf16* qptr = qb + ((size_t)n * 1024 + q0 + w * 16 + fr) * 64 + g4 * 8;
    const bf16x8 qf0 = *(const bf16x8*)qptr;
    const bf16x8 qf1 = *(const bf16x8*)(qptr + 32);

    float mval = -1e30f, lval = 0.f;
    const f32x4 z4 = {0.f, 0.f, 0.f, 0.f};
    f32x4 o[4] = {z4, z4, z4, z4};

    const int srow = t >> 3;
    const int scb  = (t & 7) ^ (srow & 7);
    const __bf16* kbase = kb + (size_t)n * 65536;
    const __bf16* vbase = vT + (size_t)n * 65536;

    gload_lds16(kbase + (size_t)srow * 64 + scb * 8,   &Kl[0][t * 8]);
    gload_lds16(vbase + (size_t)srow * 1024 + scb * 8, &Vl[0][t * 8]);
    __syncthreads();

    int cur = 0;
    for (int kc = 0; kc < 16; kc++) {
        if (kc < 15) {
            const int t0 = (kc + 1) * 64;
            gload_lds16(kbase + (size_t)(t0 + srow) * 64 + scb * 8,  &Kl[cur ^ 1][t * 8]);
            gload_lds16(vbase + (size_t)srow * 1024 + t0 + scb * 8,  &Vl[cur ^ 1][t * 8]);
        }

        // ---- QK^T (swapped): sc[tt][r] = score[key = 16tt+4g4+r][q = fr] ----
        f32x4 sc[4];
        __builtin_amdgcn_s_setprio(1);
#pragma unroll
        for (int tt = 0; tt < 4; tt++) {
            const int row = (tt * 16 + fr) * 64;
            bf16x8 kf0 = *(const bf16x8*)&Kl[cur][row + ((g4 ^ fx) * 8)];
            bf16x8 kf1 = *(const bf16x8*)&Kl[cur][row + (((4 + g4) ^ fx) * 8)];
            f32x4 s = __builtin_amdgcn_mfma_f32_16x16x32_bf16(kf0, qf0, z4, 0, 0, 0);
            s = __builtin_amdgcn_mfma_f32_16x16x32_bf16(kf1, qf1, s, 0, 0, 0);
            sc[tt] = s;
        }
        __builtin_amdgcn_s_setprio(0);

        // ---- in-lane softmax over 16 values + cross-g4 (2 shfl) ----
        float a[16];
#pragma unroll
        for (int tt = 0; tt < 4; tt++)
#pragma unroll
            for (int r = 0; r < 4; r++) a[tt * 4 + r] = sc[tt][r];

        float m8[8];
#pragma unroll
        for (int i = 0; i < 8; i++) m8[i] = fmaxf(a[i], a[i + 8]);
        float m4a = fmaxf(m8[0], m8[4]), m4b = fmaxf(m8[1], m8[5]);
        float m4c = fmaxf(m8[2], m8[6]), m4d = fmaxf(m8[3], m8[7]);
        float pmax = fmaxf(fmaxf(m4a, m4b), fmaxf(m4c, m4d));
        pmax = fmaxf(pmax, __shfl_xor(pmax, 16));
        pmax = fmaxf(pmax, __shfl_xor(pmax, 32));

        if (pmax > mval + 8.0f) {
            const float sf = __builtin_amdgcn_exp2f(mval - pmax);
            lval *= sf;
#pragma unroll
            for (int dt = 0; dt < 4; dt++) o[dt] *= sf;
            mval = pmax;
        }

        float p[16];
#pragma unroll
        for (int i = 0; i < 16; i++) p[i] = __builtin_amdgcn_exp2f(a[i] - mval);
        float s8[8];
#pragma unroll
        for (int i = 0; i < 8; i++) s8[i] = p[i] + p[i + 8];
        float s4a = s8[0] + s8[4], s4b = s8[1] + s8[5];
        float s4c = s8[2] + s8[6], s4d = s8[3] + s8[7];
        float psum = (s4a + s4b) + (s4c + s4d);
        psum += __shfl_xor(psum, 16);
        psum += __shfl_xor(psum, 32);
        lval += psum;

#pragma unroll
        for (int tt = 0; tt < 4; tt++) {
            bf16x4 pk;
            pk[0] = (__bf16)p[tt * 4 + 0];
            pk[1] = (__bf16)p[tt * 4 + 1];
            pk[2] = (__bf16)p[tt * 4 + 2];
            pk[3] = (__bf16)p[tt * 4 + 3];
            const int blk = (2 * tt + (g4 >> 1)) ^ fx;
            *(bf16x4*)&Pl[w][fr * 64 + blk * 8 + (g4 & 1) * 4] = pk;
        }

        // ---- PV (swapped): o[dt][r] -> d = 16dt+4g4+r, q = fr ----
        __builtin_amdgcn_s_setprio(1);
#pragma unroll
        for (int ks = 0; ks < 2; ks++) {
            bf16x8 pa = *(const bf16x8*)&Pl[w][fr * 64 + (((4 * ks + g4) ^ fx) * 8)];
#pragma unroll
            for (int dt = 0; dt < 4; dt++) {
                bf16x8 vf = *(const bf16x8*)&Vl[cur][(dt * 16 + fr) * 64 + (((4 * ks + g4) ^ fx) * 8)];
                o[dt] = __builtin_amdgcn_mfma_f32_16x16x32_bf16(vf, pa, o[dt], 0, 0, 0);
            }
        }
        __builtin_amdgcn_s_setprio(0);

        if (kc < 15) __syncthreads();
        cur ^= 1;
    }

    const int b = n / NH, head = n % NH;
    const float rl = 1.0f / lval;
    const int srw = q0 + w * 16 + fr;
    __bf16* cbase = ctx + ((size_t)srw * 8 + b) * 768 + head * 64;
#pragma unroll
    for (int dt = 0; dt < 4; dt++) {
        bf16x4 ov;
#pragma unroll
        for (int r = 0; r < 4; r++) ov[r] = (__bf16)(o[dt][r] * rl);
        *(bf16x4*)&cbase[dt * 16 + g4 * 4] = ov;
    }
}

extern "C" void kernel_launch(void* const* d_in, const int* in_sizes, int n_in,
                              void* d_out, int out_size, void* d_ws, size_t ws_size,
                              hipStream_t stream) {
    const float* hs = (const float*)d_in[0];
    const float* w1 = (const float*)d_in[1];
    const float* b1 = (const float*)d_in[2];
    const float* w2 = (const float*)d_in[3];
    const float* b2 = (const float*)d_in[4];
    float* out = (float*)d_out;

    char* ws = (char*)d_ws;
    __bf16* qb  = (__bf16*)(ws);
    __bf16* kb  = (__bf16*)(ws + 12582912);
    __bf16* vT  = (__bf16*)(ws + 25165824);
    __bf16* Xh  = (__bf16*)(ws + 37748736);
    __bf16* Wq  = (__bf16*)(ws + 50331648);
    __bf16* Wo  = (__bf16*)(ws + 53870592);
    __bf16* Ctx = Xh;

    convert_kernel<<<2048, 256, 0, stream>>>(hs, w1, w2, Xh, Wq, Wo);
    gemm_nt<0, 4><<<1152, 512, 0, stream>>>(Xh, Wq, b1, qb, kb, vT, nullptr, 8192, 2304, 768, 18);
    attn_kernel<<<768, 512, 0, stream>>>(qb, kb, vT, Ctx);
    gemm_nt<1, 2><<<384, 512, 0, stream>>>(Ctx, Wo, b2, nullptr, nullptr, nullptr, out, 8192, 768, 768, 6);
}

// Round 7
// 133.900 us; speedup vs baseline: 1.1070x; 1.1070x over previous
//
#include <hip/hip_runtime.h>

#define NH 12

typedef __bf16 bf16x8 __attribute__((ext_vector_type(8)));
typedef __bf16 bf16x4 __attribute__((ext_vector_type(4)));
typedef float f32x4 __attribute__((ext_vector_type(4)));

typedef const __attribute__((address_space(1))) void* gas_ptr;
typedef __attribute__((address_space(3))) void* las_ptr;

__device__ __forceinline__ void gload_lds16(const __bf16* g, __bf16* l) {
    __builtin_amdgcn_global_load_lds((gas_ptr)g, (las_ptr)l, 16, 0, 0);
}

// Q scale folded with log2(e): attention runs in exp2 domain.
#define QSCALE 0.18033688011112042f   // 0.125 * log2(e)

// ---------------- fp32 -> bf16 conversion (vectorized: 8 elems/thread/iter) ----------------
__global__ void convert_kernel(const float* __restrict__ hs,
                               const float* __restrict__ w1,
                               const float* __restrict__ w2,
                               __bf16* __restrict__ xh,
                               __bf16* __restrict__ wq,
                               __bf16* __restrict__ wo) {
    const long long C0 = 786432;   // 6291456/8
    const long long C1 = 221184;   // 1769472/8
    const long long C2 = 73728;    // 589824/8
    long long i = (long long)blockIdx.x * blockDim.x + threadIdx.x;
    const long long stride = (long long)gridDim.x * blockDim.x;
    for (; i < C0 + C1 + C2; i += stride) {
        const float* src; __bf16* dst; long long j;
        if (i < C0)           { src = hs; dst = xh; j = i; }
        else if (i < C0 + C1) { src = w1; dst = wq; j = i - C0; }
        else                  { src = w2; dst = wo; j = i - C0 - C1; }
        f32x4 v0 = *(const f32x4*)(src + j * 8);
        f32x4 v1 = *(const f32x4*)(src + j * 8 + 4);
        bf16x8 o;
#pragma unroll
        for (int r = 0; r < 4; r++) { o[r] = (__bf16)v0[r]; o[4 + r] = (__bf16)v1[r]; }
        *(bf16x8*)(dst + j * 8) = o;
    }
}

// ---------------- NT bf16 MFMA GEMM: C = A(MxK) * B(NxK)^T + bias ----------------
// BM=256 x BN=128, BK=64. 512 threads / 8 waves (4M x 2N), wave tile 64x64.
// 2-phase-per-K-tile interleave: {ds_read A+B0 || stage A(t+2) || 16 MFMA} bar
//                                {ds_read B1   || stage B(t+2) || 16 MFMA}
// NBUF=3 LDS ring (144 KB), prefetch 2 K-tiles ahead, counted vmcnt(6) at iter
// end (next tile's 6 loads retire, tile t+2's 6 stay in flight ACROSS the
// barrier). Never vmcnt(0) in steady state. XOR-swizzled LDS throughout.
template <int MODE>
__global__ __launch_bounds__(512) void gemm_nt(
    const __bf16* __restrict__ A, const __bf16* __restrict__ Bm,
    const float* __restrict__ bias,
    __bf16* __restrict__ qb, __bf16* __restrict__ kb, __bf16* __restrict__ vT,
    float* __restrict__ outf, int M, int N, int K, int NXB)
{
    __shared__ __bf16 As[3][256 * 64];   // 96 KB
    __shared__ __bf16 Bs[3][128 * 64];   // 48 KB
    const int t = threadIdx.x;
    const int lane = t & 63;
    const int w = t >> 6;
    const int wr = w >> 1, wc = w & 1;   // 4M x 2N wave grid
    const int fr = lane & 15, g4 = lane >> 4;

    const int cpx = gridDim.x >> 3;
    const int orig = blockIdx.x;
    const int swz = (orig & 7) * cpx + (orig >> 3);
    const int bx = swz % NXB, by = swz / NXB;
    const int m0 = by * 256, n0 = bx * 128;

    f32x4 acc[4][4];
    const f32x4 z4 = {0.f, 0.f, 0.f, 0.f};
#pragma unroll
    for (int i = 0; i < 4; i++)
#pragma unroll
        for (int j = 0; j < 4; j++) acc[i][j] = z4;

    const int nT = K >> 6;   // 12 for both GEMMs

    // per-thread staging slots: A 4 chunks (rows 0..255), B 2 chunks (rows 0..127)
    const __bf16* pA[4];  int ldsA[4];
    const __bf16* pB[2];  int ldsB[2];
#pragma unroll
    for (int i = 0; i < 4; i++) {
        const int c = i * 512 + t;
        const int row = c >> 3;
        const int cb = ((c & 7) ^ (row & 7)) * 8;   // pre-swizzled source chunk
        pA[i] = A + (size_t)(m0 + row) * K + cb;
        ldsA[i] = c * 8;
    }
#pragma unroll
    for (int i = 0; i < 2; i++) {
        const int c = i * 512 + t;
        const int row = c >> 3;
        const int cb = ((c & 7) ^ (row & 7)) * 8;
        pB[i] = Bm + (size_t)(n0 + row) * K + cb;
        ldsB[i] = c * 8;
    }

    auto stageA = [&](int b) {   // 4 VMEM issues, advance K by 64
#pragma unroll
        for (int i = 0; i < 4; i++) { gload_lds16(pA[i], &As[b][ldsA[i]]); pA[i] += 64; }
    };
    auto stageB = [&](int b) {   // 2 VMEM issues
#pragma unroll
        for (int i = 0; i < 2; i++) { gload_lds16(pB[i], &Bs[b][ldsB[i]]); pB[i] += 64; }
    };

    // prologue: tiles 0 and 1 in flight (12 loads), wait tile 0 (oldest 6)
    stageA(0); stageB(0);
    stageA(1); stageB(1);
    asm volatile("s_waitcnt vmcnt(6)" ::: "memory");
    __builtin_amdgcn_s_barrier();

    for (int tI = 0; tI < nT; tI++) {
        const int p = tI % 3;
        const int q = (tI + 2) % 3;
        const bool pre = (tI + 2) < nT;

        // ---- phase A: A-frags + B-half0, stage A(t+2), MFMA cols 0..1 ----
        bf16x8 af[4][2], bfr[2][2];
#pragma unroll
        for (int i = 0; i < 4; i++)
#pragma unroll
            for (int kk = 0; kk < 2; kk++) {
                const int r = wr * 64 + i * 16 + fr;
                af[i][kk] = *(const bf16x8*)&As[p][r * 64 + (((kk * 4 + g4) ^ (r & 7)) * 8)];
            }
#pragma unroll
        for (int j = 0; j < 2; j++)
#pragma unroll
            for (int kk = 0; kk < 2; kk++) {
                const int r = wc * 64 + j * 16 + fr;
                bfr[j][kk] = *(const bf16x8*)&Bs[p][r * 64 + (((kk * 4 + g4) ^ (r & 7)) * 8)];
            }
        if (pre) stageA(q);
        __builtin_amdgcn_s_setprio(1);
#pragma unroll
        for (int kk = 0; kk < 2; kk++)
#pragma unroll
            for (int i = 0; i < 4; i++)
#pragma unroll
                for (int j = 0; j < 2; j++)
                    acc[i][j] = __builtin_amdgcn_mfma_f32_16x16x32_bf16(af[i][kk], bfr[j][kk], acc[i][j], 0, 0, 0);
        __builtin_amdgcn_s_setprio(0);
        __builtin_amdgcn_s_barrier();   // lockstep

        // ---- phase B: B-half1, stage B(t+2), MFMA cols 2..3 ----
#pragma unroll
        for (int j = 0; j < 2; j++)
#pragma unroll
            for (int kk = 0; kk < 2; kk++) {
                const int r = wc * 64 + 32 + j * 16 + fr;
                bfr[j][kk] = *(const bf16x8*)&Bs[p][r * 64 + (((kk * 4 + g4) ^ (r & 7)) * 8)];
            }
        if (pre) stageB(q);
        __builtin_amdgcn_s_setprio(1);
#pragma unroll
        for (int kk = 0; kk < 2; kk++)
#pragma unroll
            for (int i = 0; i < 4; i++)
#pragma unroll
                for (int j = 0; j < 2; j++)
                    acc[i][2 + j] = __builtin_amdgcn_mfma_f32_16x16x32_bf16(af[i][kk], bfr[j][kk], acc[i][2 + j], 0, 0, 0);
        __builtin_amdgcn_s_setprio(0);

        const int rem = nT - 1 - tI;
        if (rem >= 2)      asm volatile("s_waitcnt vmcnt(6)" ::: "memory");
        else if (rem == 1) asm volatile("s_waitcnt vmcnt(0)" ::: "memory");
        if (rem >= 1) __builtin_amdgcn_s_barrier();
    }

#pragma unroll
    for (int j = 0; j < 4; j++) {
        const int gc = n0 + wc * 64 + j * 16 + fr;
        const float bv = bias[gc];
        int which = 0, head = 0, dim = 0;
        if (MODE == 0) {
            which = gc / 768;
            const int jj = gc - which * 768;
            head = jj >> 6; dim = jj & 63;
        }
#pragma unroll
        for (int i = 0; i < 4; i++)
#pragma unroll
            for (int r = 0; r < 4; r++) {
                const int gr = m0 + wr * 64 + i * 16 + g4 * 4 + r;
                const float val = acc[i][j][r] + bv;
                if (MODE == 0) {
                    const int s = gr >> 3, b = gr & 7;
                    const size_t n = (size_t)(b * NH + head);
                    if (which == 0)      qb[(n * 1024 + s) * 64 + dim] = (__bf16)(val * QSCALE);
                    else if (which == 1) kb[(n * 1024 + s) * 64 + dim] = (__bf16)val;
                    else                 vT[(n * 64 + dim) * 1024 + s] = (__bf16)val;
                } else {
                    outf[(size_t)gr * N + gc] = val;
                }
            }
    }
}

// ---------------- flash attention ----------------
__global__ __launch_bounds__(512) void attn_kernel(
    const __bf16* __restrict__ qb, const __bf16* __restrict__ kb,
    const __bf16* __restrict__ vT, __bf16* __restrict__ ctx)
{
    __shared__ __bf16 Kl[2][64 * 64];
    __shared__ __bf16 Vl[2][64 * 64];
    __shared__ __bf16 Pl[8][16 * 64];
    const int t = threadIdx.x, lane = t & 63, w = t >> 6;

    const int orig = blockIdx.x;
    const int swz = (orig & 7) * 96 + (orig >> 3);
    const int n = swz >> 3;
    const int q0 = (swz & 7) * 128;
    const int fr = lane & 15, g4 = lane >> 4;
    const int fx = fr & 7;

    const __bf16* qptr = qb + ((size_t)n * 1024 + q0 + w * 16 + fr) * 64 + g4 * 8;
    const bf16x8 qf0 = *(const bf16x8*)qptr;
    const bf16x8 qf1 = *(const bf16x8*)(qptr + 32);

    float mval = -1e30f, lval = 0.f;
    const f32x4 z4 = {0.f, 0.f, 0.f, 0.f};
    f32x4 o[4] = {z4, z4, z4, z4};

    const int srow = t >> 3;
    const int scb  = (t & 7) ^ (srow & 7);
    const __bf16* kbase = kb + (size_t)n * 65536;
    const __bf16* vbase = vT + (size_t)n * 65536;

    gload_lds16(kbase + (size_t)srow * 64 + scb * 8,   &Kl[0][t * 8]);
    gload_lds16(vbase + (size_t)srow * 1024 + scb * 8, &Vl[0][t * 8]);
    __syncthreads();

    int cur = 0;
    for (int kc = 0; kc < 16; kc++) {
        if (kc < 15) {
            const int t0 = (kc + 1) * 64;
            gload_lds16(kbase + (size_t)(t0 + srow) * 64 + scb * 8,  &Kl[cur ^ 1][t * 8]);
            gload_lds16(vbase + (size_t)srow * 1024 + t0 + scb * 8,  &Vl[cur ^ 1][t * 8]);
        }

        // ---- QK^T (swapped): sc[tt][r] = score[key = 16tt+4g4+r][q = fr] ----
        f32x4 sc[4];
        __builtin_amdgcn_s_setprio(1);
#pragma unroll
        for (int tt = 0; tt < 4; tt++) {
            const int row = (tt * 16 + fr) * 64;
            bf16x8 kf0 = *(const bf16x8*)&Kl[cur][row + ((g4 ^ fx) * 8)];
            bf16x8 kf1 = *(const bf16x8*)&Kl[cur][row + (((4 + g4) ^ fx) * 8)];
            f32x4 s = __builtin_amdgcn_mfma_f32_16x16x32_bf16(kf0, qf0, z4, 0, 0, 0);
            s = __builtin_amdgcn_mfma_f32_16x16x32_bf16(kf1, qf1, s, 0, 0, 0);
            sc[tt] = s;
        }
        __builtin_amdgcn_s_setprio(0);

        // ---- in-lane softmax over 16 values + cross-g4 (2 shfl) ----
        float a[16];
#pragma unroll
        for (int tt = 0; tt < 4; tt++)
#pragma unroll
            for (int r = 0; r < 4; r++) a[tt * 4 + r] = sc[tt][r];

        float m8[8];
#pragma unroll
        for (int i = 0; i < 8; i++) m8[i] = fmaxf(a[i], a[i + 8]);
        float m4a = fmaxf(m8[0], m8[4]), m4b = fmaxf(m8[1], m8[5]);
        float m4c = fmaxf(m8[2], m8[6]), m4d = fmaxf(m8[3], m8[7]);
        float pmax = fmaxf(fmaxf(m4a, m4b), fmaxf(m4c, m4d));
        pmax = fmaxf(pmax, __shfl_xor(pmax, 16));
        pmax = fmaxf(pmax, __shfl_xor(pmax, 32));

        if (pmax > mval + 8.0f) {
            const float sf = __builtin_amdgcn_exp2f(mval - pmax);
            lval *= sf;
#pragma unroll
            for (int dt = 0; dt < 4; dt++) o[dt] *= sf;
            mval = pmax;
        }

        float p[16];
#pragma unroll
        for (int i = 0; i < 16; i++) p[i] = __builtin_amdgcn_exp2f(a[i] - mval);
        float s8[8];
#pragma unroll
        for (int i = 0; i < 8; i++) s8[i] = p[i] + p[i + 8];
        float s4a = s8[0] + s8[4], s4b = s8[1] + s8[5];
        float s4c = s8[2] + s8[6], s4d = s8[3] + s8[7];
        float psum = (s4a + s4b) + (s4c + s4d);
        psum += __shfl_xor(psum, 16);
        psum += __shfl_xor(psum, 32);
        lval += psum;

#pragma unroll
        for (int tt = 0; tt < 4; tt++) {
            bf16x4 pk;
            pk[0] = (__bf16)p[tt * 4 + 0];
            pk[1] = (__bf16)p[tt * 4 + 1];
            pk[2] = (__bf16)p[tt * 4 + 2];
            pk[3] = (__bf16)p[tt * 4 + 3];
            const int blk = (2 * tt + (g4 >> 1)) ^ fx;
            *(bf16x4*)&Pl[w][fr * 64 + blk * 8 + (g4 & 1) * 4] = pk;
        }

        // ---- PV (swapped): o[dt][r] -> d = 16dt+4g4+r, q = fr ----
        __builtin_amdgcn_s_setprio(1);
#pragma unroll
        for (int ks = 0; ks < 2; ks++) {
            bf16x8 pa = *(const bf16x8*)&Pl[w][fr * 64 + (((4 * ks + g4) ^ fx) * 8)];
#pragma unroll
            for (int dt = 0; dt < 4; dt++) {
                bf16x8 vf = *(const bf16x8*)&Vl[cur][(dt * 16 + fr) * 64 + (((4 * ks + g4) ^ fx) * 8)];
                o[dt] = __builtin_amdgcn_mfma_f32_16x16x32_bf16(vf, pa, o[dt], 0, 0, 0);
            }
        }
        __builtin_amdgcn_s_setprio(0);

        if (kc < 15) __syncthreads();
        cur ^= 1;
    }

    const int b = n / NH, head = n % NH;
    const float rl = 1.0f / lval;
    const int srw = q0 + w * 16 + fr;
    __bf16* cbase = ctx + ((size_t)srw * 8 + b) * 768 + head * 64;
#pragma unroll
    for (int dt = 0; dt < 4; dt++) {
        bf16x4 ov;
#pragma unroll
        for (int r = 0; r < 4; r++) ov[r] = (__bf16)(o[dt][r] * rl);
        *(bf16x4*)&cbase[dt * 16 + g4 * 4] = ov;
    }
}

extern "C" void kernel_launch(void* const* d_in, const int* in_sizes, int n_in,
                              void* d_out, int out_size, void* d_ws, size_t ws_size,
                              hipStream_t stream) {
    const float* hs = (const float*)d_in[0];
    const float* w1 = (const float*)d_in[1];
    const float* b1 = (const float*)d_in[2];
    const float* w2 = (const float*)d_in[3];
    const float* b2 = (const float*)d_in[4];
    float* out = (float*)d_out;

    char* ws = (char*)d_ws;
    __bf16* qb  = (__bf16*)(ws);
    __bf16* kb  = (__bf16*)(ws + 12582912);
    __bf16* vT  = (__bf16*)(ws + 25165824);
    __bf16* Xh  = (__bf16*)(ws + 37748736);
    __bf16* Wq  = (__bf16*)(ws + 50331648);
    __bf16* Wo  = (__bf16*)(ws + 53870592);
    __bf16* Ctx = Xh;

    convert_kernel<<<2048, 256, 0, stream>>>(hs, w1, w2, Xh, Wq, Wo);
    gemm_nt<0><<<576, 512, 0, stream>>>(Xh, Wq, b1, qb, kb, vT, nullptr, 8192, 2304, 768, 18);
    attn_kernel<<<768, 512, 0, stream>>>(qb, kb, vT, Ctx);
    gemm_nt<1><<<192, 512, 0, stream>>>(Ctx, Wo, b2, nullptr, nullptr, nullptr, out, 8192, 768, 768, 6);
}